// Round 3
// baseline (198.180 us; speedup 1.0000x reference)
//
#include <hip/hip_runtime.h>
#include <math.h>

#define TEMP_INV (1.0f / 0.07f)

typedef float vf4 __attribute__((ext_vector_type(4)));

__device__ __forceinline__ float wave_reduce_sum(float v) {
    #pragma unroll
    for (int off = 32; off; off >>= 1) v += __shfl_down(v, off);
    return v;
}

__device__ __forceinline__ float wave_reduce_max(float v) {
    #pragma unroll
    for (int off = 32; off; off >>= 1) v = fmaxf(v, __shfl_down(v, off));
    return v;
}

// Fused: row stats (first rowBlocks blocks) + negative raw sims (rest).
//   raw[j] = dot(neg_j, anchor_b) * inv_norm(neg_j) / T   (anchor norm deferred)
__global__ void k_stats(const float* __restrict__ A, const float* __restrict__ P,
                        const float* __restrict__ Ng, const int* __restrict__ idx,
                        float* __restrict__ inv_na, float* __restrict__ pos_sim,
                        float* __restrict__ raw, int* __restrict__ counter,
                        int B, int N, int rowBlocks) {
    if (blockIdx.x == 0 && threadIdx.x == 0) *counter = 0;  // reset for k_seg_final
    int wib  = threadIdx.x >> 6;
    int lane = threadIdx.x & 63;
    if ((int)blockIdx.x < rowBlocks) {
        int b = blockIdx.x * 4 + wib;
        if (b >= B) return;
        const float4 a = reinterpret_cast<const float4*>(A + (size_t)b * 256)[lane];
        const float4 p = reinterpret_cast<const float4*>(P + (size_t)b * 256)[lane];
        float sa = a.x * a.x + a.y * a.y + a.z * a.z + a.w * a.w;
        float sp = p.x * p.x + p.y * p.y + p.z * p.z + p.w * p.w;
        float dp = a.x * p.x + a.y * p.y + a.z * p.z + a.w * p.w;
        sa = wave_reduce_sum(sa);
        sp = wave_reduce_sum(sp);
        dp = wave_reduce_sum(dp);
        if (lane == 0) {
            float ia = 1.0f / fmaxf(sqrtf(sa), 1e-12f);
            float ip = 1.0f / fmaxf(sqrtf(sp), 1e-12f);
            inv_na[b]  = ia;
            pos_sim[b] = dp * ia * ip * TEMP_INV;
        }
    } else {
        int j = ((int)blockIdx.x - rowBlocks) * 4 + wib;
        if (j >= N) return;
        int b = idx[j];
        const vf4* nrow = reinterpret_cast<const vf4*>(Ng + (size_t)j * 256);
        const vf4 n4 = __builtin_nontemporal_load(nrow + lane);  // 128MB stream, no reuse
        const float4 a4 = reinterpret_cast<const float4*>(A + (size_t)b * 256)[lane];
        float sn = n4.x * n4.x + n4.y * n4.y + n4.z * n4.z + n4.w * n4.w;
        float dp = a4.x * n4.x + a4.y * n4.y + a4.z * n4.z + a4.w * n4.w;
        sn = wave_reduce_sum(sn);
        dp = wave_reduce_sum(dp);
        if (lane == 0) {
            float in_ = 1.0f / fmaxf(sqrtf(sn), 1e-12f);
            raw[j] = dp * in_ * TEMP_INV;   // anchor inv-norm applied in k_seg_final
        }
    }
}

// One wave (block of 64) per batch row: segment max + LSE; last block reduces.
__global__ void k_seg_final(const int* __restrict__ idx, const float* __restrict__ raw,
                            const float* __restrict__ inv_na, const float* __restrict__ pos_sim,
                            float* __restrict__ loss_i, float* __restrict__ corr,
                            int* __restrict__ counter, float* __restrict__ out,
                            int B, int N) {
    int b = blockIdx.x;
    int lane = threadIdx.x;  // blockDim.x == 64

    // lower_bound(idx, b), lower_bound(idx, b+1) — idx sorted
    int lo = 0, hi = N;
    while (lo < hi) { int mid = (lo + hi) >> 1; if (idx[mid] < b) lo = mid + 1; else hi = mid; }
    int s = lo;
    lo = s; hi = N;
    while (lo < hi) { int mid = (lo + hi) >> 1; if (idx[mid] < b + 1) lo = mid + 1; else hi = mid; }
    int e = lo;

    float ps = pos_sim[b];
    float ia = inv_na[b];

    float l_val = 0.0f, c_val = 0.0f;
    if (e > s) {
        float mxr = -INFINITY;
        for (int j = s + lane; j < e; j += 64) mxr = fmaxf(mxr, raw[j]);
        mxr = wave_reduce_max(mxr);
        mxr = __shfl(mxr, 0);
        float mx = mxr * ia;              // ia > 0 -> order preserved

        float m = fmaxf(ps, mx);
        float se = 0.0f;
        for (int j = s + lane; j < e; j += 64) se += expf(raw[j] * ia - m);
        se = wave_reduce_sum(se);
        se = __shfl(se, 0);

        l_val = -ps + m + logf(se + expf(ps - m));
        c_val = (ps > mx) ? 1.0f : 0.0f;
    }
    if (lane == 0) { loss_i[b] = l_val; corr[b] = c_val; }

    // last-block-done final reduce (deterministic: one block, fixed order)
    __threadfence();
    int done = 0;
    if (lane == 0) done = (atomicAdd(counter, 1) == B - 1) ? 1 : 0;
    done = __shfl(done, 0);
    if (!done) return;
    __threadfence();

    float l = 0.0f, c = 0.0f;
    for (int i = lane; i < B; i += 64) { l += loss_i[i]; c += corr[i]; }
    l = wave_reduce_sum(l);
    c = wave_reduce_sum(c);
    if (lane == 0) {
        out[0] = l / (float)B;
        out[1] = c / (float)B;
    }
}

extern "C" void kernel_launch(void* const* d_in, const int* in_sizes, int n_in,
                              void* d_out, int out_size, void* d_ws, size_t ws_size,
                              hipStream_t stream) {
    const float* anchor    = (const float*)d_in[0];
    const float* positive  = (const float*)d_in[1];
    const float* negatives = (const float*)d_in[2];
    const int*   idx       = (const int*)d_in[3];

    const int D = 256;
    const int B = in_sizes[0] / D;   // 4096
    const int N = in_sizes[2] / D;   // 131072

    float* ws      = (float*)d_ws;
    float* raw     = ws;               // N
    float* inv_na  = ws + N;           // B
    float* pos_sim = ws + N + B;       // B
    float* loss_i  = ws + N + 2 * B;   // B
    float* corr    = ws + N + 3 * B;   // B
    int*   counter = (int*)(ws + N + 4 * B);  // 1

    float* out = (float*)d_out;

    int rowBlocks = (B + 3) / 4;
    int negBlocks = (N + 3) / 4;

    k_stats<<<rowBlocks + negBlocks, 256, 0, stream>>>(
        anchor, positive, negatives, idx, inv_na, pos_sim, raw, counter, B, N, rowBlocks);

    k_seg_final<<<B, 64, 0, stream>>>(idx, raw, inv_na, pos_sim, loss_i, corr,
                                      counter, out, B, N);
}

// Round 4
// 55.032 us; speedup vs baseline: 3.6012x; 3.6012x over previous
//
#include <hip/hip_runtime.h>
#include <math.h>

#define TEMP_INV (1.0f / 0.07f)

typedef float vf4 __attribute__((ext_vector_type(4)));

__device__ __forceinline__ float wave_reduce_sum(float v) {
    #pragma unroll
    for (int off = 32; off; off >>= 1) v += __shfl_down(v, off);
    return v;
}

__device__ __forceinline__ float wave_reduce_max(float v) {
    #pragma unroll
    for (int off = 32; off; off >>= 1) v = fmaxf(v, __shfl_down(v, off));
    return v;
}

// Fused: row stats (first rowBlocks blocks) + negative raw sims (rest).
//   raw[j] = dot(neg_j, anchor_b) * inv_norm(neg_j) / T   (anchor norm deferred)
__global__ void k_stats(const float* __restrict__ A, const float* __restrict__ P,
                        const float* __restrict__ Ng, const int* __restrict__ idx,
                        float* __restrict__ inv_na, float* __restrict__ pos_sim,
                        float* __restrict__ raw, int B, int N, int rowBlocks) {
    int wib  = threadIdx.x >> 6;
    int lane = threadIdx.x & 63;
    if ((int)blockIdx.x < rowBlocks) {
        int b = blockIdx.x * 4 + wib;
        if (b >= B) return;
        const float4 a = reinterpret_cast<const float4*>(A + (size_t)b * 256)[lane];
        const float4 p = reinterpret_cast<const float4*>(P + (size_t)b * 256)[lane];
        float sa = a.x * a.x + a.y * a.y + a.z * a.z + a.w * a.w;
        float sp = p.x * p.x + p.y * p.y + p.z * p.z + p.w * p.w;
        float dp = a.x * p.x + a.y * p.y + a.z * p.z + a.w * p.w;
        sa = wave_reduce_sum(sa);
        sp = wave_reduce_sum(sp);
        dp = wave_reduce_sum(dp);
        if (lane == 0) {
            float ia = 1.0f / fmaxf(sqrtf(sa), 1e-12f);
            float ip = 1.0f / fmaxf(sqrtf(sp), 1e-12f);
            inv_na[b]  = ia;
            pos_sim[b] = dp * ia * ip * TEMP_INV;
        }
    } else {
        int j = ((int)blockIdx.x - rowBlocks) * 4 + wib;
        if (j >= N) return;
        int b = idx[j];
        const vf4* nrow = reinterpret_cast<const vf4*>(Ng + (size_t)j * 256);
        const vf4 n4 = __builtin_nontemporal_load(nrow + lane);  // 128MB stream, no reuse
        const float4 a4 = reinterpret_cast<const float4*>(A + (size_t)b * 256)[lane];
        float sn = n4.x * n4.x + n4.y * n4.y + n4.z * n4.z + n4.w * n4.w;
        float dp = a4.x * n4.x + a4.y * n4.y + a4.z * n4.z + a4.w * n4.w;
        sn = wave_reduce_sum(sn);
        dp = wave_reduce_sum(dp);
        if (lane == 0) {
            float in_ = 1.0f / fmaxf(sqrtf(sn), 1e-12f);
            raw[j] = dp * in_ * TEMP_INV;   // anchor inv-norm applied in k_seg
        }
    }
}

// One wave (block of 64) per batch row: segment max + LSE.
__global__ void k_seg(const int* __restrict__ idx, const float* __restrict__ raw,
                      const float* __restrict__ inv_na, const float* __restrict__ pos_sim,
                      float* __restrict__ loss_i, float* __restrict__ corr,
                      int B, int N) {
    int b = blockIdx.x;
    int lane = threadIdx.x;  // blockDim.x == 64

    // lower_bound(idx, b), lower_bound(idx, b+1) — idx sorted
    int lo = 0, hi = N;
    while (lo < hi) { int mid = (lo + hi) >> 1; if (idx[mid] < b) lo = mid + 1; else hi = mid; }
    int s = lo;
    lo = s; hi = N;
    while (lo < hi) { int mid = (lo + hi) >> 1; if (idx[mid] < b + 1) lo = mid + 1; else hi = mid; }
    int e = lo;

    float ps = pos_sim[b];
    float ia = inv_na[b];

    float l_val = 0.0f, c_val = 0.0f;
    if (e > s) {
        float mxr = -INFINITY;
        for (int j = s + lane; j < e; j += 64) mxr = fmaxf(mxr, raw[j]);
        mxr = wave_reduce_max(mxr);
        mxr = __shfl(mxr, 0);
        float mx = mxr * ia;              // ia > 0 -> order preserved

        float m = fmaxf(ps, mx);
        float se = 0.0f;
        for (int j = s + lane; j < e; j += 64) se += expf(raw[j] * ia - m);
        se = wave_reduce_sum(se);
        se = __shfl(se, 0);

        l_val = -ps + m + logf(se + expf(ps - m));
        c_val = (ps > mx) ? 1.0f : 0.0f;
    }
    if (lane == 0) { loss_i[b] = l_val; corr[b] = c_val; }
}

// Single-block deterministic reduce -> out[0]=loss, out[1]=accuracy
__global__ void k_final(const float* __restrict__ loss_i, const float* __restrict__ corr,
                        float* __restrict__ out, int B) {
    __shared__ float sl[256];
    __shared__ float sc[256];
    float l = 0.0f, c = 0.0f;
    for (int i = threadIdx.x; i < B; i += 256) { l += loss_i[i]; c += corr[i]; }
    sl[threadIdx.x] = l; sc[threadIdx.x] = c;
    __syncthreads();
    for (int s = 128; s; s >>= 1) {
        if ((int)threadIdx.x < s) {
            sl[threadIdx.x] += sl[threadIdx.x + s];
            sc[threadIdx.x] += sc[threadIdx.x + s];
        }
        __syncthreads();
    }
    if (threadIdx.x == 0) {
        out[0] = sl[0] / (float)B;
        out[1] = sc[0] / (float)B;
    }
}

extern "C" void kernel_launch(void* const* d_in, const int* in_sizes, int n_in,
                              void* d_out, int out_size, void* d_ws, size_t ws_size,
                              hipStream_t stream) {
    const float* anchor    = (const float*)d_in[0];
    const float* positive  = (const float*)d_in[1];
    const float* negatives = (const float*)d_in[2];
    const int*   idx       = (const int*)d_in[3];

    const int D = 256;
    const int B = in_sizes[0] / D;   // 4096
    const int N = in_sizes[2] / D;   // 131072

    float* ws      = (float*)d_ws;
    float* raw     = ws;               // N
    float* inv_na  = ws + N;           // B
    float* pos_sim = ws + N + B;       // B
    float* loss_i  = ws + N + 2 * B;   // B
    float* corr    = ws + N + 3 * B;   // B

    float* out = (float*)d_out;

    int rowBlocks = (B + 3) / 4;
    int negBlocks = (N + 3) / 4;

    k_stats<<<rowBlocks + negBlocks, 256, 0, stream>>>(
        anchor, positive, negatives, idx, inv_na, pos_sim, raw, B, N, rowBlocks);

    k_seg<<<B, 64, 0, stream>>>(idx, raw, inv_na, pos_sim, loss_i, corr, B, N);

    k_final<<<1, 256, 0, stream>>>(loss_i, corr, out, B);
}

// Round 5
// 43.611 us; speedup vs baseline: 4.5442x; 1.2619x over previous
//
#include <hip/hip_runtime.h>
#include <math.h>

#define TEMP_INV (1.0f / 0.07f)   // also used as the fixed LSE shift M

typedef float vf4 __attribute__((ext_vector_type(4)));

__device__ __forceinline__ float wave_reduce_sum(float v) {
    #pragma unroll
    for (int off = 32; off; off >>= 1) v += __shfl_down(v, off);
    return v;
}

__device__ __forceinline__ float wave_reduce_max(float v) {
    #pragma unroll
    for (int off = 32; off; off >>= 1) v = fmaxf(v, __shfl_down(v, off));
    return v;
}

// Fused: row stats (first rowBlocks blocks) + negative raw sims (rest, 2 rows/wave).
//   raw[j] = dot(neg_j, anchor_b) * inv_norm(neg_j) / T   (anchor norm deferred)
__global__ void k_stats(const float* __restrict__ A, const float* __restrict__ P,
                        const float* __restrict__ Ng, const int* __restrict__ idx,
                        float* __restrict__ inv_na, float* __restrict__ pos_sim,
                        float* __restrict__ raw, int B, int N, int rowBlocks) {
    int wib  = threadIdx.x >> 6;
    int lane = threadIdx.x & 63;
    if ((int)blockIdx.x < rowBlocks) {
        int b = blockIdx.x * 4 + wib;
        if (b >= B) return;
        const float4 a = reinterpret_cast<const float4*>(A + (size_t)b * 256)[lane];
        const float4 p = reinterpret_cast<const float4*>(P + (size_t)b * 256)[lane];
        float sa = a.x * a.x + a.y * a.y + a.z * a.z + a.w * a.w;
        float sp = p.x * p.x + p.y * p.y + p.z * p.z + p.w * p.w;
        float dp = a.x * p.x + a.y * p.y + a.z * p.z + a.w * p.w;
        sa = wave_reduce_sum(sa);
        sp = wave_reduce_sum(sp);
        dp = wave_reduce_sum(dp);
        if (lane == 0) {
            float ia = 1.0f / fmaxf(sqrtf(sa), 1e-12f);
            float ip = 1.0f / fmaxf(sqrtf(sp), 1e-12f);
            inv_na[b]  = ia;
            pos_sim[b] = dp * ia * ip * TEMP_INV;
        }
    } else {
        int w = ((int)blockIdx.x - rowBlocks) * 4 + wib;  // wave id, handles j0, j0+1
        int j0 = w * 2;
        if (j0 >= N) return;
        int b0 = idx[j0];
        int b1 = idx[j0 + 1];   // N is even; j0+1 < N
        const vf4* n0p = reinterpret_cast<const vf4*>(Ng + (size_t)j0 * 256);
        const vf4* n1p = reinterpret_cast<const vf4*>(Ng + (size_t)(j0 + 1) * 256);
        const vf4 n0 = __builtin_nontemporal_load(n0p + lane);
        const vf4 n1 = __builtin_nontemporal_load(n1p + lane);
        const float4 a0 = reinterpret_cast<const float4*>(A + (size_t)b0 * 256)[lane];
        const float4 a1 = reinterpret_cast<const float4*>(A + (size_t)b1 * 256)[lane];
        float sn0 = n0.x * n0.x + n0.y * n0.y + n0.z * n0.z + n0.w * n0.w;
        float dp0 = a0.x * n0.x + a0.y * n0.y + a0.z * n0.z + a0.w * n0.w;
        float sn1 = n1.x * n1.x + n1.y * n1.y + n1.z * n1.z + n1.w * n1.w;
        float dp1 = a1.x * n1.x + a1.y * n1.y + a1.z * n1.z + a1.w * n1.w;
        sn0 = wave_reduce_sum(sn0);
        dp0 = wave_reduce_sum(dp0);
        sn1 = wave_reduce_sum(sn1);
        dp1 = wave_reduce_sum(dp1);
        if (lane == 0) {
            raw[j0]     = dp0 * (1.0f / fmaxf(sqrtf(sn0), 1e-12f)) * TEMP_INV;
            raw[j0 + 1] = dp1 * (1.0f / fmaxf(sqrtf(sn1), 1e-12f)) * TEMP_INV;
        }
    }
}

// One wave per batch row: single-pass segment max + fixed-M exp-sum.
__global__ void k_seg(const int* __restrict__ idx, const float* __restrict__ raw,
                      const float* __restrict__ inv_na, const float* __restrict__ pos_sim,
                      float* __restrict__ loss_i, float* __restrict__ corr,
                      int B, int N) {
    int b = blockIdx.x;
    int lane = threadIdx.x;  // blockDim.x == 64

    // lower_bound(idx, b) — idx sorted
    int lo = 0, hi = N;
    while (lo < hi) { int mid = (lo + hi) >> 1; if (idx[mid] < b) lo = mid + 1; else hi = mid; }
    int s = lo;

    // gallop for e: first position >= b+1 (coalesced 64-wide rounds)
    int e = s;
    for (int base = s;; base += 64) {
        int pos = base + lane;
        int v = (pos < N) ? idx[pos] : 0x7fffffff;
        unsigned long long m = __ballot(v >= b + 1);
        if (m) { e = base + (int)(__ffsll((long long)m)) - 1; break; }
    }

    float ps = pos_sim[b];
    float ia = inv_na[b];

    float l_val = 0.0f, c_val = 0.0f;
    if (e > s) {
        const float M = TEMP_INV;  // fixed shift; sims bounded by 1/T
        float mx = -INFINITY, se = 0.0f;
        for (int j = s + lane; j < e; j += 64) {
            float t = raw[j] * ia;
            mx = fmaxf(mx, t);
            se += expf(t - M);
        }
        mx = wave_reduce_max(mx);
        se = wave_reduce_sum(se);
        mx = __shfl(mx, 0);
        se = __shfl(se, 0);
        l_val = -ps + M + logf(se + expf(ps - M));
        c_val = (ps > mx) ? 1.0f : 0.0f;
    }
    if (lane == 0) { loss_i[b] = l_val; corr[b] = c_val; }
}

// Single-block deterministic reduce -> out[0]=loss, out[1]=accuracy
__global__ void k_final(const float* __restrict__ loss_i, const float* __restrict__ corr,
                        float* __restrict__ out, int B) {
    __shared__ float sl[256];
    __shared__ float sc[256];
    float l = 0.0f, c = 0.0f;
    for (int i = threadIdx.x; i < B; i += 256) { l += loss_i[i]; c += corr[i]; }
    sl[threadIdx.x] = l; sc[threadIdx.x] = c;
    __syncthreads();
    for (int s = 128; s; s >>= 1) {
        if ((int)threadIdx.x < s) {
            sl[threadIdx.x] += sl[threadIdx.x + s];
            sc[threadIdx.x] += sc[threadIdx.x + s];
        }
        __syncthreads();
    }
    if (threadIdx.x == 0) {
        out[0] = sl[0] / (float)B;
        out[1] = sc[0] / (float)B;
    }
}

extern "C" void kernel_launch(void* const* d_in, const int* in_sizes, int n_in,
                              void* d_out, int out_size, void* d_ws, size_t ws_size,
                              hipStream_t stream) {
    const float* anchor    = (const float*)d_in[0];
    const float* positive  = (const float*)d_in[1];
    const float* negatives = (const float*)d_in[2];
    const int*   idx       = (const int*)d_in[3];

    const int D = 256;
    const int B = in_sizes[0] / D;   // 4096
    const int N = in_sizes[2] / D;   // 131072

    float* ws      = (float*)d_ws;
    float* raw     = ws;               // N
    float* inv_na  = ws + N;           // B
    float* pos_sim = ws + N + B;       // B
    float* loss_i  = ws + N + 2 * B;   // B
    float* corr    = ws + N + 3 * B;   // B

    float* out = (float*)d_out;

    int rowBlocks = (B + 3) / 4;                 // 1024
    int negBlocks = (N / 2 + 3) / 4;             // 16384 (2 rows per wave)

    k_stats<<<rowBlocks + negBlocks, 256, 0, stream>>>(
        anchor, positive, negatives, idx, inv_na, pos_sim, raw, B, N, rowBlocks);

    k_seg<<<B, 64, 0, stream>>>(idx, raw, inv_na, pos_sim, loss_i, corr, B, N);

    k_final<<<1, 256, 0, stream>>>(loss_i, corr, out, B);
}

// Round 6
// 38.138 us; speedup vs baseline: 5.1964x; 1.1435x over previous
//
#include <hip/hip_runtime.h>
#include <math.h>

#define TEMP_INV (1.0f / 0.07f)   // also the fixed LSE shift M (sims bounded by 1/T)

typedef float vf4 __attribute__((ext_vector_type(4)));

__device__ __forceinline__ float wave_reduce_sum(float v) {
    #pragma unroll
    for (int off = 32; off; off >>= 1) v += __shfl_down(v, off);
    return v;
}

__device__ __forceinline__ float wave_reduce_max(float v) {
    #pragma unroll
    for (int off = 32; off; off >>= 1) v = fmaxf(v, __shfl_down(v, off));
    return v;
}

// Fused kernel, three block regions:
//   [0, rowBlocks)            : per-row anchor/positive stats (4 waves/block)
//   [rowBlocks, +segBlocks)   : fill seg_start[0..B] from sorted idx (grid-stride)
//   [rowBlocks+segBlocks, end): negative raw sims, persistent waves, 4 rows/iter
__global__ void k_stats(const float* __restrict__ A, const float* __restrict__ P,
                        const float* __restrict__ Ng, const int* __restrict__ idx,
                        float* __restrict__ inv_na, float* __restrict__ pos_sim,
                        float* __restrict__ raw, int* __restrict__ seg_start,
                        int B, int N, int rowBlocks, int segBlocks, int negBlocks) {
    int bid  = (int)blockIdx.x;
    int wib  = threadIdx.x >> 6;
    int lane = threadIdx.x & 63;

    if (bid < rowBlocks) {
        int b = bid * 4 + wib;
        if (b >= B) return;
        const float4 a = reinterpret_cast<const float4*>(A + (size_t)b * 256)[lane];
        const float4 p = reinterpret_cast<const float4*>(P + (size_t)b * 256)[lane];
        float sa = a.x * a.x + a.y * a.y + a.z * a.z + a.w * a.w;
        float sp = p.x * p.x + p.y * p.y + p.z * p.z + p.w * p.w;
        float dp = a.x * p.x + a.y * p.y + a.z * p.z + a.w * p.w;
        sa = wave_reduce_sum(sa);
        sp = wave_reduce_sum(sp);
        dp = wave_reduce_sum(dp);
        if (lane == 0) {
            float ia = 1.0f / fmaxf(sqrtf(sa), 1e-12f);
            float ip = 1.0f / fmaxf(sqrtf(sp), 1e-12f);
            inv_na[b]  = ia;
            pos_sim[b] = dp * ia * ip * TEMP_INV;
        }
    } else if (bid < rowBlocks + segBlocks) {
        // seg_start[v] = lower_bound(idx, v) for v in [0, B]
        int t0 = (bid - rowBlocks) * 256 + (int)threadIdx.x;
        int nthreads = segBlocks * 256;
        for (int j = t0; j <= N; j += nthreads) {
            if (j == 0) {
                int c = idx[0];
                for (int v = 0; v <= c; ++v) seg_start[v] = 0;
            } else if (j < N) {
                int prev = idx[j - 1], cur = idx[j];
                for (int v = prev + 1; v <= cur; ++v) seg_start[v] = j;
            } else {  // j == N
                int prev = idx[N - 1];
                for (int v = prev + 1; v <= B; ++v) seg_start[v] = N;
            }
        }
    } else {
        int wave    = (bid - rowBlocks - segBlocks) * 4 + wib;
        int nwaves  = negBlocks * 4;
        int nchunks = N >> 2;  // 4 rows per chunk (N % 4 == 0)
        for (int chunk = wave; chunk < nchunks; chunk += nwaves) {
            int j0 = chunk * 4;
            int b0 = idx[j0], b1 = idx[j0 + 1], b2 = idx[j0 + 2], b3 = idx[j0 + 3];
            const vf4 n0 = __builtin_nontemporal_load(
                reinterpret_cast<const vf4*>(Ng + (size_t)j0 * 256) + lane);
            const vf4 n1 = __builtin_nontemporal_load(
                reinterpret_cast<const vf4*>(Ng + (size_t)(j0 + 1) * 256) + lane);
            const vf4 n2 = __builtin_nontemporal_load(
                reinterpret_cast<const vf4*>(Ng + (size_t)(j0 + 2) * 256) + lane);
            const vf4 n3 = __builtin_nontemporal_load(
                reinterpret_cast<const vf4*>(Ng + (size_t)(j0 + 3) * 256) + lane);
            const float4 a0 = reinterpret_cast<const float4*>(A + (size_t)b0 * 256)[lane];
            const float4 a1 = reinterpret_cast<const float4*>(A + (size_t)b1 * 256)[lane];
            const float4 a2 = reinterpret_cast<const float4*>(A + (size_t)b2 * 256)[lane];
            const float4 a3 = reinterpret_cast<const float4*>(A + (size_t)b3 * 256)[lane];

            float sn0 = n0.x*n0.x + n0.y*n0.y + n0.z*n0.z + n0.w*n0.w;
            float sn1 = n1.x*n1.x + n1.y*n1.y + n1.z*n1.z + n1.w*n1.w;
            float sn2 = n2.x*n2.x + n2.y*n2.y + n2.z*n2.z + n2.w*n2.w;
            float sn3 = n3.x*n3.x + n3.y*n3.y + n3.z*n3.z + n3.w*n3.w;
            float dp0 = a0.x*n0.x + a0.y*n0.y + a0.z*n0.z + a0.w*n0.w;
            float dp1 = a1.x*n1.x + a1.y*n1.y + a1.z*n1.z + a1.w*n1.w;
            float dp2 = a2.x*n2.x + a2.y*n2.y + a2.z*n2.z + a2.w*n2.w;
            float dp3 = a3.x*n3.x + a3.y*n3.y + a3.z*n3.z + a3.w*n3.w;

            sn0 = wave_reduce_sum(sn0); dp0 = wave_reduce_sum(dp0);
            sn1 = wave_reduce_sum(sn1); dp1 = wave_reduce_sum(dp1);
            sn2 = wave_reduce_sum(sn2); dp2 = wave_reduce_sum(dp2);
            sn3 = wave_reduce_sum(sn3); dp3 = wave_reduce_sum(dp3);

            if (lane == 0) {
                raw[j0]     = dp0 * (1.0f / fmaxf(sqrtf(sn0), 1e-12f)) * TEMP_INV;
                raw[j0 + 1] = dp1 * (1.0f / fmaxf(sqrtf(sn1), 1e-12f)) * TEMP_INV;
                raw[j0 + 2] = dp2 * (1.0f / fmaxf(sqrtf(sn2), 1e-12f)) * TEMP_INV;
                raw[j0 + 3] = dp3 * (1.0f / fmaxf(sqrtf(sn3), 1e-12f)) * TEMP_INV;
            }
        }
    }
}

// One wave per batch row (4 rows per 256-thread block): fixed-M single-pass LSE.
__global__ void k_seg(const float* __restrict__ raw, const int* __restrict__ seg_start,
                      const float* __restrict__ inv_na, const float* __restrict__ pos_sim,
                      float* __restrict__ loss_i, float* __restrict__ corr, int B) {
    int b = (int)blockIdx.x * 4 + (threadIdx.x >> 6);
    int lane = threadIdx.x & 63;
    if (b >= B) return;

    int s = seg_start[b];
    int e = seg_start[b + 1];

    float ps = pos_sim[b];
    float ia = inv_na[b];

    float l_val = 0.0f, c_val = 0.0f;
    if (e > s) {
        const float M = TEMP_INV;
        float mx = -INFINITY, se = 0.0f;
        for (int j = s + lane; j < e; j += 64) {
            float t = raw[j] * ia;
            mx = fmaxf(mx, t);
            se += expf(t - M);
        }
        mx = wave_reduce_max(mx);
        se = wave_reduce_sum(se);
        mx = __shfl(mx, 0);
        se = __shfl(se, 0);
        l_val = -ps + M + logf(se + expf(ps - M));
        c_val = (ps > mx) ? 1.0f : 0.0f;
    }
    if (lane == 0) { loss_i[b] = l_val; corr[b] = c_val; }
}

// Single-block deterministic reduce -> out[0]=loss, out[1]=accuracy
__global__ void k_final(const float* __restrict__ loss_i, const float* __restrict__ corr,
                        float* __restrict__ out, int B) {
    __shared__ float sl[256];
    __shared__ float sc[256];
    float l = 0.0f, c = 0.0f;
    for (int i = threadIdx.x; i < B; i += 256) { l += loss_i[i]; c += corr[i]; }
    sl[threadIdx.x] = l; sc[threadIdx.x] = c;
    __syncthreads();
    for (int s = 128; s; s >>= 1) {
        if ((int)threadIdx.x < s) {
            sl[threadIdx.x] += sl[threadIdx.x + s];
            sc[threadIdx.x] += sc[threadIdx.x + s];
        }
        __syncthreads();
    }
    if (threadIdx.x == 0) {
        out[0] = sl[0] / (float)B;
        out[1] = sc[0] / (float)B;
    }
}

extern "C" void kernel_launch(void* const* d_in, const int* in_sizes, int n_in,
                              void* d_out, int out_size, void* d_ws, size_t ws_size,
                              hipStream_t stream) {
    const float* anchor    = (const float*)d_in[0];
    const float* positive  = (const float*)d_in[1];
    const float* negatives = (const float*)d_in[2];
    const int*   idx       = (const int*)d_in[3];

    const int D = 256;
    const int B = in_sizes[0] / D;   // 4096
    const int N = in_sizes[2] / D;   // 131072

    float* ws        = (float*)d_ws;
    float* raw       = ws;                // N
    float* inv_na    = ws + N;            // B
    float* pos_sim   = ws + N + B;        // B
    float* loss_i    = ws + N + 2 * B;    // B
    float* corr      = ws + N + 3 * B;    // B
    int*   seg_start = (int*)(ws + N + 4 * B);  // B + 1

    float* out = (float*)d_out;

    int rowBlocks = (B + 3) / 4;   // 1024
    int segBlocks = 64;
    int negBlocks = 2048;          // persistent: 8192 waves, 4 rows/iter

    k_stats<<<rowBlocks + segBlocks + negBlocks, 256, 0, stream>>>(
        anchor, positive, negatives, idx, inv_na, pos_sim, raw, seg_start,
        B, N, rowBlocks, segBlocks, negBlocks);

    k_seg<<<(B + 3) / 4, 256, 0, stream>>>(raw, seg_start, inv_na, pos_sim,
                                           loss_i, corr, B);

    k_final<<<1, 256, 0, stream>>>(loss_i, corr, out, B);
}

// Round 7
// 34.192 us; speedup vs baseline: 5.7960x; 1.1154x over previous
//
#include <hip/hip_runtime.h>
#include <math.h>

#define TEMP_INV (1.0f / 0.07f)   // also the fixed LSE shift M (sims bounded by 1/T)

typedef float vf4 __attribute__((ext_vector_type(4)));

__device__ __forceinline__ float wave_reduce_sum(float v) {
    #pragma unroll
    for (int off = 32; off; off >>= 1) v += __shfl_down(v, off);
    return v;
}

__device__ __forceinline__ float wave_reduce_max(float v) {
    #pragma unroll
    for (int off = 32; off; off >>= 1) v = fmaxf(v, __shfl_down(v, off));
    return v;
}

// fold two value-streams into one register: lanes with (lane&span) carry hi's
// partial sums, others lo's. After all rounds value k lives in lane-group k.
__device__ __forceinline__ float merge2(float lo, float hi, int span, int lane) {
    float a = lo + __shfl_xor(lo, span);
    float b = hi + __shfl_xor(hi, span);
    return (lane & span) ? b : a;
}

// One persistent kernel: each wave does (1) one anchor/positive row, (2) its
// seg_start share, (3) grid-strided negative chunks (4 rows / 4KB per iter).
__global__ void k_main(const float* __restrict__ A, const float* __restrict__ P,
                       const float* __restrict__ Ng, const int* __restrict__ idx,
                       float* __restrict__ inv_na, float* __restrict__ pos_sim,
                       float* __restrict__ raw, int* __restrict__ seg_start,
                       int B, int N) {
    const int bid  = (int)blockIdx.x;
    const int wib  = threadIdx.x >> 6;
    const int lane = threadIdx.x & 63;
    const int wave = bid * 4 + wib;
    const int nwaves = (int)gridDim.x * 4;

    // ---- Phase 1: row stats (one row per wave; B <= nwaves) ----
    if (wave < B) {
        int b = wave;
        const float4 a = reinterpret_cast<const float4*>(A + (size_t)b * 256)[lane];
        const float4 p = reinterpret_cast<const float4*>(P + (size_t)b * 256)[lane];
        float sa = a.x * a.x + a.y * a.y + a.z * a.z + a.w * a.w;
        float sp = p.x * p.x + p.y * p.y + p.z * p.z + p.w * p.w;
        float dq = a.x * p.x + a.y * p.y + a.z * p.z + a.w * p.w;
        sa = wave_reduce_sum(sa);
        sp = wave_reduce_sum(sp);
        dq = wave_reduce_sum(dq);
        if (lane == 0) {
            float ia = 1.0f / fmaxf(sqrtf(sa), 1e-12f);
            float ip = 1.0f / fmaxf(sqrtf(sp), 1e-12f);
            inv_na[b]  = ia;
            pos_sim[b] = dq * ia * ip * TEMP_INV;
        }
    }

    // ---- Phase 2: seg_start[v] = lower_bound(idx, v), v in [0,B] ----
    {
        int t = bid * 256 + (int)threadIdx.x;
        int stride = (int)gridDim.x * 256;
        for (int j = t; j <= N; j += stride) {
            if (j == 0) {
                int c = idx[0];
                for (int v = 0; v <= c; ++v) seg_start[v] = 0;
            } else if (j < N) {
                int prev = idx[j - 1], cur = idx[j];
                for (int v = prev + 1; v <= cur; ++v) seg_start[v] = j;
            } else {
                int prev = idx[N - 1];
                for (int v = prev + 1; v <= B; ++v) seg_start[v] = N;
            }
        }
    }

    // ---- Phase 3: negative sims, 4 rows per iteration ----
    const int nchunks = N >> 2;
    const float4* A4 = reinterpret_cast<const float4*>(A);
    for (int chunk = wave; chunk < nchunks; chunk += nwaves) {
        int j0 = chunk << 2;
        int4 bi = *reinterpret_cast<const int4*>(idx + j0);
        int b0 = __builtin_amdgcn_readfirstlane(bi.x);
        int b1 = __builtin_amdgcn_readfirstlane(bi.y);
        int b2 = __builtin_amdgcn_readfirstlane(bi.z);
        int b3 = __builtin_amdgcn_readfirstlane(bi.w);

        const vf4 n0 = __builtin_nontemporal_load(
            reinterpret_cast<const vf4*>(Ng + (size_t)j0 * 256) + lane);
        const vf4 n1 = __builtin_nontemporal_load(
            reinterpret_cast<const vf4*>(Ng + (size_t)(j0 + 1) * 256) + lane);
        const vf4 n2 = __builtin_nontemporal_load(
            reinterpret_cast<const vf4*>(Ng + (size_t)(j0 + 2) * 256) + lane);
        const vf4 n3 = __builtin_nontemporal_load(
            reinterpret_cast<const vf4*>(Ng + (size_t)(j0 + 3) * 256) + lane);

        float4 a0 = A4[(size_t)b0 * 64 + lane];
        float4 a1, a2, a3;
        if (b3 == b0) {            // wave-uniform scalar branch; common case
            a1 = a0; a2 = a0; a3 = a0;
        } else {
            a1 = A4[(size_t)b1 * 64 + lane];
            a2 = A4[(size_t)b2 * 64 + lane];
            a3 = A4[(size_t)b3 * 64 + lane];
        }

        float sn0 = n0.x*n0.x + n0.y*n0.y + n0.z*n0.z + n0.w*n0.w;
        float dp0 = a0.x*n0.x + a0.y*n0.y + a0.z*n0.z + a0.w*n0.w;
        float sn1 = n1.x*n1.x + n1.y*n1.y + n1.z*n1.z + n1.w*n1.w;
        float dp1 = a1.x*n1.x + a1.y*n1.y + a1.z*n1.z + a1.w*n1.w;
        float sn2 = n2.x*n2.x + n2.y*n2.y + n2.z*n2.z + n2.w*n2.w;
        float dp2 = a2.x*n2.x + a2.y*n2.y + a2.z*n2.z + a2.w*n2.w;
        float sn3 = n3.x*n3.x + n3.y*n3.y + n3.z*n3.z + n3.w*n3.w;
        float dp3 = a3.x*n3.x + a3.y*n3.y + a3.z*n3.z + a3.w*n3.w;

        // 8-value fold: 17 shuffles total. Final layout:
        //   sn_r -> lanes [16r,16r+8), dp_r -> lanes [16r+8,16r+16)
        float nv0 = merge2(sn0, sn2, 32, lane);
        float nv1 = merge2(dp0, dp2, 32, lane);
        float nv2 = merge2(sn1, sn3, 32, lane);
        float nv3 = merge2(dp1, dp3, 32, lane);
        float m0  = merge2(nv0, nv2, 16, lane);
        float m1  = merge2(nv1, nv3, 16, lane);
        float f   = merge2(m0,  m1,   8, lane);
        f += __shfl_xor(f, 4);
        f += __shfl_xor(f, 2);
        f += __shfl_xor(f, 1);

        float fdp = __shfl_down(f, 8);   // lane 16r receives dp_r
        if ((lane & 15) == 0) {
            int r = lane >> 4;
            raw[j0 + r] = fdp * (1.0f / fmaxf(sqrtf(f), 1e-12f)) * TEMP_INV;
        }
    }
}

// One wave per batch row (4 rows per 256-thread block): fixed-M single-pass LSE.
__global__ void k_seg(const float* __restrict__ raw, const int* __restrict__ seg_start,
                      const float* __restrict__ inv_na, const float* __restrict__ pos_sim,
                      float* __restrict__ loss_i, float* __restrict__ corr, int B) {
    int b = (int)blockIdx.x * 4 + (threadIdx.x >> 6);
    int lane = threadIdx.x & 63;
    if (b >= B) return;

    int s = seg_start[b];
    int e = seg_start[b + 1];

    float ps = pos_sim[b];
    float ia = inv_na[b];

    float l_val = 0.0f, c_val = 0.0f;
    if (e > s) {
        const float M = TEMP_INV;
        float mx = -INFINITY, se = 0.0f;
        for (int j = s + lane; j < e; j += 64) {
            float t = raw[j] * ia;
            mx = fmaxf(mx, t);
            se += expf(t - M);
        }
        mx = wave_reduce_max(mx);
        se = wave_reduce_sum(se);
        mx = __shfl(mx, 0);
        se = __shfl(se, 0);
        l_val = -ps + M + logf(se + expf(ps - M));
        c_val = (ps > mx) ? 1.0f : 0.0f;
    }
    if (lane == 0) { loss_i[b] = l_val; corr[b] = c_val; }
}

// Single-block deterministic reduce -> out[0]=loss, out[1]=accuracy
__global__ void k_final(const float* __restrict__ loss_i, const float* __restrict__ corr,
                        float* __restrict__ out, int B) {
    __shared__ float sl[16];
    __shared__ float sc[16];
    int tid = (int)threadIdx.x, lane = tid & 63, wid = tid >> 6;  // 16 waves
    float l = 0.0f, c = 0.0f;
    for (int i = tid; i < B; i += 1024) { l += loss_i[i]; c += corr[i]; }
    l = wave_reduce_sum(l);
    c = wave_reduce_sum(c);
    if (lane == 0) { sl[wid] = l; sc[wid] = c; }
    __syncthreads();
    if (wid == 0) {
        float lv = (lane < 16) ? sl[lane] : 0.0f;
        float cv = (lane < 16) ? sc[lane] : 0.0f;
        lv = wave_reduce_sum(lv);
        cv = wave_reduce_sum(cv);
        if (lane == 0) {
            out[0] = lv / (float)B;
            out[1] = cv / (float)B;
        }
    }
}

extern "C" void kernel_launch(void* const* d_in, const int* in_sizes, int n_in,
                              void* d_out, int out_size, void* d_ws, size_t ws_size,
                              hipStream_t stream) {
    const float* anchor    = (const float*)d_in[0];
    const float* positive  = (const float*)d_in[1];
    const float* negatives = (const float*)d_in[2];
    const int*   idx       = (const int*)d_in[3];

    const int D = 256;
    const int B = in_sizes[0] / D;   // 4096
    const int N = in_sizes[2] / D;   // 131072

    float* ws        = (float*)d_ws;
    float* raw       = ws;                // N
    float* inv_na    = ws + N;            // B
    float* pos_sim   = ws + N + B;        // B
    float* loss_i    = ws + N + 2 * B;    // B
    float* corr      = ws + N + 3 * B;    // B
    int*   seg_start = (int*)(ws + N + 4 * B);  // B + 1

    float* out = (float*)d_out;

    // 2048 blocks x 256 threads = exact machine fill (8 blocks/CU x 256 CU)
    k_main<<<2048, 256, 0, stream>>>(anchor, positive, negatives, idx,
                                     inv_na, pos_sim, raw, seg_start, B, N);

    k_seg<<<(B + 3) / 4, 256, 0, stream>>>(raw, seg_start, inv_na, pos_sim,
                                           loss_i, corr, B);

    k_final<<<1, 1024, 0, stream>>>(loss_i, corr, out, B);
}